// Round 4
// baseline (224.147 us; speedup 1.0000x reference)
//
#include <hip/hip_runtime.h>
#include <stdint.h>

#define SLEN 2048
#define EMB  1024
#define NHEAD 16
#define HDIM  64
#define WINSZ 128

typedef __attribute__((ext_vector_type(8))) __bf16 bf16x8;
typedef __attribute__((ext_vector_type(4))) float  f32x4;

__device__ __forceinline__ unsigned short f2bf(float f) {
  union { float f; unsigned int u; } v;
  v.f = f;
  unsigned int r = v.u + 0x7FFFu + ((v.u >> 16) & 1u);
  return (unsigned short)(r >> 16);
}

// pack two floats to bf16 pair (round-half-up; inputs finite, in [0,1] for P)
__device__ __forceinline__ unsigned int pack_bf(float a, float b) {
  union { float f; unsigned int u; } x, y;
  x.f = a; y.f = b;
  return ((y.u + 0x8000u) & 0xFFFF0000u) | ((x.u + 0x8000u) >> 16);
}

// One fused convert for x, w_in, w_out -> contiguous bf16 region at ws base.
__global__ void cvt_all(const float* __restrict__ x,
                        const float* __restrict__ wi,
                        const float* __restrict__ wo,
                        unsigned short* __restrict__ dst) {
  const long n0 = 8388608, n1 = n0 + 3145728, n2 = n1 + 1048576;
  long i = ((long)blockIdx.x * 256 + threadIdx.x) * 4;
  if (i >= n2) return;
  const float* src; long off;
  if (i < n0)      { src = x;  off = i; }
  else if (i < n1) { src = wi; off = i - n0; }
  else             { src = wo; off = i - n1; }
  float4 f = *(const float4*)(src + off);
  ushort4 o;
  o.x = f2bf(f.x); o.y = f2bf(f.y); o.z = f2bf(f.z); o.w = f2bf(f.w);
  *(ushort4*)(dst + i) = o;
}

#define AS1(p) (const __attribute__((address_space(1))) unsigned int*)((const void*)(p))
#define AS3(p) (__attribute__((address_space(3))) unsigned int*)((void*)(p))

// C = A[M,K] * B[N,K]^T + bias.  m201-geometry port: tile 256x256, BK=64,
// 512 thr = 8 waves (2M x 4N), per-wave 128x64 (8x4 frags, B-frags
// register-reused across M-halves -> 22.9 KiB LDS-read per MFLOP vs 30.5
// for 64x64 waves; LDS-BW was the measured round-3 bound).
// LDS: 5 half-tile slots x 32 KiB = 160 KiB.  Half h = A rows
// [(h&1)*128,+128) + B rows [(h&1)*128,+128) of K-tile (h>>1), slot h%5.
// Rows are 128 B, chunk-XOR swizzled via pre-swizzled global source
// (round-0 geometry, measured ZERO bank conflicts).
// Pipeline: during tile T stage halves 2T+3 (phases 0-1) and 2T+4
// (phases 2-3), 2 gload_lds/wave/phase.  Tile-boundary wait vmcnt(4)
// (halves 2T+2,2T+3 drained, 2T+4 stays in flight); vmcnt(0) only
// entering the last tile.  4 phases/tile (kstep x M-half), 16 MFMA each,
// barrier-pair + lgkmcnt(0) + sched_barrier + setprio per phase.
// MODE 0: fp32 out at ldc.  MODE 1 (qkv): cols <2048 -> bf16 at
// row-stride 2048; cols >=2048 (V) -> transposed into vt[b][h][d][s].
template <int MODE>
__global__ __launch_bounds__(512, 2) void gemm_nt(
    const unsigned short* __restrict__ A,
    const unsigned short* __restrict__ B,
    const float* __restrict__ bias,
    void* __restrict__ Cout,
    unsigned short* __restrict__ vt,
    int M, int N, int K, int ldc)
{
  __shared__ unsigned short lds[81920];   // 5 slots x 16384 ush = 160 KiB
  const int tid  = threadIdx.x;
  const int wave = tid >> 6, lane = tid & 63;
  const int quad = lane >> 4, l16 = lane & 15;
  const int wm2 = (wave >> 2) * 128;      // wave's C-row base (A-half)
  const int wn2 = (wave & 3) * 64;        // wave's C-col base
  const int ah  = wave >> 2;              // A-half parity used by this wave
  const int bh  = (wave & 3) >> 1;        // B-half parity used by this wave
  const int brow = (wave & 1) * 64;       // B row base within its half
  const int swz = l16 & 7;

  // bijective XCD-aware block swizzle (nwg % 8 == 0 for both modes)
  const int nwgx = gridDim.x;
  const int nwg  = nwgx * gridDim.y;
  const int orig = blockIdx.y * nwgx + blockIdx.x;
  const int bswz = (orig & 7) * (nwg >> 3) + (orig >> 3);
  const long mBase = (long)(bswz / nwgx) * 256;
  const long nBase = (long)(bswz % nwgx) * 256;

  // staging lane geometry: one instr = 8 rows x 64 cols, source col
  // pre-swizzled so linear LDS dest gets the chunk-XOR layout.
  const int lr  = lane >> 3;
  const int lks = ((lane & 7) ^ lr) * 8;
  const unsigned short* Abase = A + (mBase + lr) * (long)K + lks;
  const unsigned short* Bbase = B + (nBase + lr) * (long)K + lks;

  const int NT = K >> 6;   // >= 3

  // STAGE_PART(half, slot, part): part 0/1 = A rows (w*16,+8)/(+8,+16),
  // part 2/3 = same for B.  Guard keeps barrier counts uniform (scalar).
#define STAGE_PART(HH, SL, P) do {                                                   \
    if ((HH) < 2 * NT) {                                                             \
      const int _r = wave * 16 + ((P) & 1) * 8;                                      \
      const long _off = ((long)(((HH) & 1) * 128 + _r)) * K + (long)((HH) >> 1) * 64;\
      if ((P) < 2)                                                                   \
        __builtin_amdgcn_global_load_lds(AS1(Abase + _off),                          \
            AS3(lds + (SL) * 16384 + _r * 64), 16, 0, 0);                            \
      else                                                                           \
        __builtin_amdgcn_global_load_lds(AS1(Bbase + _off),                          \
            AS3(lds + (SL) * 16384 + 8192 + _r * 64), 16, 0, 0);                     \
    }                                                                                \
  } while (0)

  f32x4 acc[8][4];
#pragma unroll
  for (int i = 0; i < 8; ++i)
#pragma unroll
    for (int j = 0; j < 4; ++j)
#pragma unroll
      for (int r = 0; r < 4; ++r) acc[i][j][r] = 0.f;

  // prologue: halves 0,1,2 (slots 0,1,2) = 12 instrs/wave; drain 0,1.
#pragma unroll
  for (int h = 0; h < 3; ++h) {
    STAGE_PART(h, h, 0); STAGE_PART(h, h, 1);
    STAGE_PART(h, h, 2); STAGE_PART(h, h, 3);
  }
  asm volatile("s_waitcnt vmcnt(4)" ::: "memory");
  __builtin_amdgcn_s_barrier();

  int slA = ah, slB = bh;    // slots of this wave's A/B halves for tile T
  int s3 = 3, s4 = 4;        // slots of halves 2T+3, 2T+4
  for (int T = 0; T < NT; ++T) {
    const unsigned short* Ar = lds + slA * 16384;
    const unsigned short* Br = lds + slB * 16384 + 8192 + brow * 64;
    bf16x8 bF[4];
#pragma unroll
    for (int q = 0; q < 4; ++q) {
      const int s = q >> 1, mh = q & 1;
      if (mh == 0) {
#pragma unroll
        for (int j = 0; j < 4; ++j)
          bF[j] = *(const bf16x8*)(Br + (j * 16 + l16) * 64 + (((s * 4 + quad) ^ swz) * 8));
      }
      bf16x8 aF[4];
#pragma unroll
      for (int t = 0; t < 4; ++t)
        aF[t] = *(const bf16x8*)(Ar + ((mh * 4 + t) * 16 + l16) * 64 + (((s * 4 + quad) ^ swz) * 8));

      // stage 2 pieces of half 2T+3 (q<2) or 2T+4 (q>=2)
      {
        const int hh = 2 * T + 3 + s;
        const int sl = s ? s4 : s3;
        STAGE_PART(hh, sl, mh * 2);
        STAGE_PART(hh, sl, mh * 2 + 1);
      }
      if (q == 3) {
        if (T == NT - 2)     asm volatile("s_waitcnt vmcnt(0)" ::: "memory");
        else if (T < NT - 2) asm volatile("s_waitcnt vmcnt(4)" ::: "memory");
      }
      __builtin_amdgcn_s_barrier();
      asm volatile("s_waitcnt lgkmcnt(0)" ::: "memory");
      __builtin_amdgcn_sched_barrier(0);
      __builtin_amdgcn_s_setprio(1);
#pragma unroll
      for (int t = 0; t < 4; ++t)
#pragma unroll
        for (int j = 0; j < 4; ++j)
          acc[mh * 4 + t][j] =
              __builtin_amdgcn_mfma_f32_16x16x32_bf16(aF[t], bF[j], acc[mh * 4 + t][j], 0, 0, 0);
      __builtin_amdgcn_s_setprio(0);
      __builtin_amdgcn_s_barrier();
    }
    slA += 2; if (slA >= 5) slA -= 5;
    slB += 2; if (slB >= 5) slB -= 5;
    s3  += 2; if (s3  >= 5) s3  -= 5;
    s4  += 2; if (s4  >= 5) s4  -= 5;
  }
#undef STAGE_PART

  if (MODE == 1 && nBase >= 2048) {
    // V block: write transposed into vt[b][h][d][s]; r=0..3 -> s contiguous
#pragma unroll
    for (int j = 0; j < 4; ++j) {
      const int nG = (int)nBase + wn2 + j * 16 + l16;
      const float bv = bias[nG];
      const int hd = nG - 2048;
      const int hh = hd >> 6, dd = hd & 63;
#pragma unroll
      for (int i = 0; i < 8; ++i) {
        const int mG0 = (int)mBase + wm2 + i * 16 + quad * 4;
        const int bb = mG0 >> 11, ss = mG0 & 2047;
        ushort4 o;
        o.x = f2bf(acc[i][j][0] + bv);
        o.y = f2bf(acc[i][j][1] + bv);
        o.z = f2bf(acc[i][j][2] + bv);
        o.w = f2bf(acc[i][j][3] + bv);
        *(ushort4*)(vt + (((long)(bb * NHEAD + hh)) * HDIM + dd) * SLEN + ss) = o;
      }
    }
  } else {
#pragma unroll
    for (int j = 0; j < 4; ++j) {
      const long nG = nBase + wn2 + j * 16 + l16;
      const float bv = bias[nG];
#pragma unroll
      for (int i = 0; i < 8; ++i)
#pragma unroll
        for (int r = 0; r < 4; ++r) {
          const long mG = mBase + wm2 + i * 16 + quad * 4 + r;
          const float v = acc[i][j][r] + bv;
          if (MODE == 1) ((unsigned short*)Cout)[mG * ldc + nG] = f2bf(v);
          else           ((float*)Cout)[mG * ldc + nG] = v;
        }
    }
  }
}

// Banded-causal flash attention, S^T orientation, batched softmax.
// 128-query blocks (512 thr, 8 waves). qk: [B*S][2048] bf16 (Q|K),
// vT: [B*H][64][2048]. K and V staged in XOR-swizzled LDS (GEMM-proven
// conflict-free geometry: 128B-multiple row stride + 16B-chunk XOR).
__global__ __launch_bounds__(512, 4) void local_attn(
    const unsigned short* __restrict__ qk,
    const unsigned short* __restrict__ vT,
    unsigned short* __restrict__ outw)
{
  const int qb = blockIdx.x;   // 128-query tile
  const int h  = blockIdx.y;
  const int b  = blockIdx.z;
  const int tid = threadIdx.x;
  const int wave = tid >> 6, lane = tid & 63;
  const int quad = lane >> 4, l16 = lane & 15;

  __shared__ unsigned short Klds[256 * 64];   // [key][chunk ^ (key&7)]
  __shared__ unsigned short Vlds[64 * 256];   // [d][chunk ^ (d&7)] along key

  const int kwin0 = qb * 128 - WINSZ;         // global key of local key 0

  // --- K staging via global_load_lds (swizzled, clamped rows) ---
  {
    const int kr = lane >> 3, kc = lane & 7;
    const long colOff = 1024 + h * HDIM + ((kc ^ kr) * 8);
#pragma unroll
    for (int t = 0; t < 4; ++t) {
      const int u = wave * 4 + t;                 // unit of 8 keys (32 units)
      const int sk = max(kwin0 + u * 8 + kr, 0);  // clamp; junk masked later
      const unsigned short* g = qk + (long)(b * SLEN + sk) * 2048 + colOff;
      __builtin_amdgcn_global_load_lds(AS1(g), AS3(Klds + u * 512), 16, 0, 0);
    }
  }
  // --- V^T staging: coalesced reads from vT, XOR-swizzled LDS writes ---
  {
    const unsigned short* vbase = vT + ((long)(b * NHEAD + h)) * HDIM * SLEN;
#pragma unroll
    for (int t = 0; t < 4; ++t) {
      const int c = t * 512 + tid;          // [0, 2048): 64 d x 32 chunks
      const int d = c >> 5, k8 = c & 31;
      const int s0 = max(kwin0 + k8 * 8, 0);
      uint4 v = *(const uint4*)(vbase + (long)d * SLEN + s0);
      *(uint4*)(Vlds + d * 256 + ((k8 ^ (d & 7)) * 8)) = v;
    }
  }

  // Q fragments (B-operand): 16 queries per wave
  const int q0 = qb * 128 + wave * 16;
  const long qrow = (long)(b * SLEN + q0 + l16) * 2048 + h * HDIM;
  const bf16x8 qB0 = *(const bf16x8*)(qk + qrow + quad * 8);
  const bf16x8 qB1 = *(const bf16x8*)(qk + qrow + 32 + quad * 8);

  __syncthreads();

  // --- QK^T (S^T orientation): all 5 x 32 keys ---
  const int lbase = (wave * 16) & ~31;
  const int kx = l16 & 7;
  const int a0 = (quad ^ kx) * 8;
  const int a1 = ((4 + quad) ^ kx) * 8;
  f32x4 sc[5][2];
#pragma unroll
  for (int it = 0; it < 5; ++it) {
    const int l0 = lbase + it * 32;
#pragma unroll
    for (int half = 0; half < 2; ++half) {
      const unsigned short* kr_ = Klds + (l0 + half * 16 + l16) * 64;
      const bf16x8 kA0 = *(const bf16x8*)(kr_ + a0);
      const bf16x8 kA1 = *(const bf16x8*)(kr_ + a1);
      f32x4 s;
#pragma unroll
      for (int r = 0; r < 4; ++r) s[r] = 0.f;
      s = __builtin_amdgcn_mfma_f32_16x16x32_bf16(kA0, qB0, s, 0, 0, 0);
      s = __builtin_amdgcn_mfma_f32_16x16x32_bf16(kA1, qB1, s, 0, 0, 0);
      sc[it][half] = s;   // row = key_local = quad*4+r, col = query = l16
    }
  }

  // --- mask + scale; batched softmax (reduce over quads: 2 shfl steps) ---
  // Valid local keys for query: [qlocal - WINSZ, qlocal], clipped below
  // -kwin0 when staging clamped (qb==0 -> 128).
  const int qlocal = WINSZ + wave * 16 + l16;       // own query, local coords
  const int lo = max(wave * 16 + l16, kwin0 < 0 ? -kwin0 : 0);
  const int kb = lbase + quad * 4;
  float m = -3.0e38f;
#pragma unroll
  for (int it = 0; it < 5; ++it)
#pragma unroll
    for (int half = 0; half < 2; ++half)
#pragma unroll
      for (int r = 0; r < 4; ++r) {
        const int kl = kb + it * 32 + half * 16 + r;
        float v = sc[it][half][r] * 0.125f;
        v = (kl >= lo && kl <= qlocal) ? v : -3.0e38f;
        sc[it][half][r] = v;
        m = fmaxf(m, v);
      }
  m = fmaxf(m, __shfl_xor(m, 16, 64));
  m = fmaxf(m, __shfl_xor(m, 32, 64));

  float lsum = 0.f;
#pragma unroll
  for (int it = 0; it < 5; ++it)
#pragma unroll
    for (int half = 0; half < 2; ++half)
#pragma unroll
      for (int r = 0; r < 4; ++r) {
        const float e = __expf(sc[it][half][r] - m);
        sc[it][half][r] = e;
        lsum += e;
      }
  lsum += __shfl_xor(lsum, 16, 64);
  lsum += __shfl_xor(lsum, 32, 64);
  const float invl = 1.0f / lsum;

  // --- PV: O^T = V^T * P^T; P^T B-frag assembled via shuffles ---
  f32x4 Oacc[4];
#pragma unroll
  for (int dt = 0; dt < 4; ++dt)
#pragma unroll
    for (int r = 0; r < 4; ++r) Oacc[dt][r] = 0.f;

#pragma unroll
  for (int it = 0; it < 5; ++it) {
    const int l0 = lbase + it * 32;
    // pack this lane's 8 P values (4 per half) into bf16 pairs
    const unsigned int u0 = pack_bf(sc[it][0][0], sc[it][0][1]);
    const unsigned int u1 = pack_bf(sc[it][0][2], sc[it][0][3]);
    const unsigned int u2 = pack_bf(sc[it][1][0], sc[it][1][1]);
    const unsigned int u3 = pack_bf(sc[it][1][2], sc[it][1][3]);
    // gather B-frag: lane needs keys quad*8 + [0..7] of query l16
    unsigned int breg[4];
#pragma unroll
    for (int r = 0; r < 4; ++r) {
      const int srcl = ((quad & 1) * 2 + (r >> 1)) * 16 + l16;
      const unsigned int ga = __shfl((int)((r & 1) ? u1 : u0), srcl, 64);
      const unsigned int gb = __shfl((int)((r & 1) ? u3 : u2), srcl, 64);
      breg[r] = (quad >> 1) ? gb : ga;
    }
    union { unsigned int u[4]; bf16x8 v; } pB;
    pB.u[0] = breg[0]; pB.u[1] = breg[1]; pB.u[2] = breg[2]; pB.u[3] = breg[3];

    const int chBase = (l0 >> 3);                 // multiple of 4
#pragma unroll
    for (int dt = 0; dt < 4; ++dt) {
      const int ch = (chBase + quad) ^ kx;        // kx = l16&7 = d&7
      const bf16x8 vA = *(const bf16x8*)(Vlds + (dt * 16 + l16) * 256 + ch * 8);
      Oacc[dt] = __builtin_amdgcn_mfma_f32_16x16x32_bf16(vA, pB.v, Oacc[dt], 0, 0, 0);
    }
  }

  // --- epilogue: O^T C-layout; r=0..3 contiguous -> packed ushort4 stores ---
  const long obase = (long)(b * SLEN + q0 + l16) * EMB + h * HDIM;
#pragma unroll
  for (int dt = 0; dt < 4; ++dt) {
    ushort4 o;
    o.x = f2bf(Oacc[dt][0] * invl);
    o.y = f2bf(Oacc[dt][1] * invl);
    o.z = f2bf(Oacc[dt][2] * invl);
    o.w = f2bf(Oacc[dt][3] * invl);
    *(ushort4*)(outw + obase + dt * 16 + quad * 4) = o;
  }
}

extern "C" void kernel_launch(void* const* d_in, const int* in_sizes, int n_in,
                              void* d_out, int out_size, void* d_ws, size_t ws_size,
                              hipStream_t stream) {
  const float* x     = (const float*)d_in[0];
  const float* w_in  = (const float*)d_in[1];
  const float* b_in  = (const float*)d_in[2];
  const float* w_out = (const float*)d_in[3];
  const float* b_out = (const float*)d_in[4];
  float* out = (float*)d_out;

  char* ws = (char*)d_ws;
  unsigned short* xb    = (unsigned short*)(ws + 0);          // 16,777,216
  unsigned short* winb  = (unsigned short*)(ws + 16777216);   //  6,291,456
  unsigned short* woutb = (unsigned short*)(ws + 23068672);   //  2,097,152
  unsigned short* qkb   = (unsigned short*)(ws + 25165824);   // 8192x2048 bf16 = 33,554,432
  unsigned short* attn  = (unsigned short*)(ws + 58720256);   // 16,777,216
  unsigned short* vT    = (unsigned short*)(ws + 75497472);   // 16,777,216  (total 92,274,688)

  // fused converts: dst regions are contiguous (xb|winb|woutb)
  const long ncv = 8388608 + 3145728 + 1048576;               // 12,582,912
  cvt_all<<<(int)(ncv / 1024), 256, 0, stream>>>(x, w_in, w_out, xb);

  // qkv projection: Q,K -> qkb (stride 2048); V -> vT transposed
  gemm_nt<1><<<dim3(3072 / 256, 8192 / 256), 512, 0, stream>>>(
      xb, winb, b_in, (void*)qkb, vT, 8192, 3072, 1024, 2048);

  local_attn<<<dim3(SLEN / 128, NHEAD, 4), 512, 0, stream>>>(qkb, vT, attn);

  gemm_nt<0><<<dim3(1024 / 256, 8192 / 256), 512, 0, stream>>>(
      attn, woutb, b_out, (void*)out, nullptr, 8192, 1024, 1024, 1024);
}

// Round 6
// 212.798 us; speedup vs baseline: 1.0533x; 1.0533x over previous
//
#include <hip/hip_runtime.h>
#include <stdint.h>

#define SLEN 2048
#define EMB  1024
#define NHEAD 16
#define HDIM  64
#define WINSZ 128

typedef __attribute__((ext_vector_type(8))) __bf16 bf16x8;
typedef __attribute__((ext_vector_type(4))) float  f32x4;

__device__ __forceinline__ unsigned short f2bf(float f) {
  union { float f; unsigned int u; } v;
  v.f = f;
  unsigned int r = v.u + 0x7FFFu + ((v.u >> 16) & 1u);
  return (unsigned short)(r >> 16);
}

// pack two floats to bf16 pair (round-half-up; inputs finite, in [0,1] for P)
__device__ __forceinline__ unsigned int pack_bf(float a, float b) {
  union { float f; unsigned int u; } x, y;
  x.f = a; y.f = b;
  return ((y.u + 0x8000u) & 0xFFFF0000u) | ((x.u + 0x8000u) >> 16);
}

// One fused convert for x, w_in, w_out -> contiguous bf16 region at ws base.
__global__ void cvt_all(const float* __restrict__ x,
                        const float* __restrict__ wi,
                        const float* __restrict__ wo,
                        unsigned short* __restrict__ dst) {
  const long n0 = 8388608, n1 = n0 + 3145728, n2 = n1 + 1048576;
  long i = ((long)blockIdx.x * 256 + threadIdx.x) * 4;
  if (i >= n2) return;
  const float* src; long off;
  if (i < n0)      { src = x;  off = i; }
  else if (i < n1) { src = wi; off = i - n0; }
  else             { src = wo; off = i - n1; }
  float4 f = *(const float4*)(src + off);
  ushort4 o;
  o.x = f2bf(f.x); o.y = f2bf(f.y); o.z = f2bf(f.z); o.w = f2bf(f.w);
  *(ushort4*)(dst + i) = o;
}

#define AS1(p) (const __attribute__((address_space(1))) unsigned int*)((const void*)(p))
#define AS3(p) (__attribute__((address_space(3))) unsigned int*)((void*)(p))

// C = A[M,K] * B[N,K]^T + bias.  Tile BM x 256, BK=64, 512 thr = 8 waves
// (2M x 4N), per-wave (BM/2) x 64.  BM=256 for the big QKV gemm (384
// blocks), BM=128 for the out-proj (grid 4x64 = 256 blocks = exactly one
// full round).  LDS: 5 half-tile slots; half h = A rows [(h&1)*BM/2,+BM/2)
// + B rows [(h&1)*128,+128) of K-tile (h>>1), slot h%5.  Rows 128 B,
// chunk-XOR swizzle via pre-swizzled global source (measured ZERO bank
// conflicts).  Pipeline: during tile T stage halves 2T+3 (phases 0-1) and
// 2T+4 (phases 2-3); tile-boundary wait vmcnt(HLOADS) leaves half 2T+4 in
// flight (~3-phase lookahead for every staged load); vmcnt(0) only at
// T==NT-2.  4 phases/tile (kstep x M-half), MR/2*4 MFMA each, barrier +
// lgkmcnt(0) + setprio per phase.  NO sched_barrier(0): compiler ds_reads
// carry their own deps; pinning the schedule costs ~40% (m141 analog —
// the round-4 regression).
template <int MODE, int BM>
__global__ __launch_bounds__(512, 2) void gemm_nt(
    const unsigned short* __restrict__ A,
    const unsigned short* __restrict__ B,
    const float* __restrict__ bias,
    void* __restrict__ Cout,
    unsigned short* __restrict__ vt,
    int M, int N, int K, int ldc)
{
  constexpr int MR     = BM / 32;           // acc frag-rows per wave (8|4)
  constexpr int HA     = BM / 2;            // A rows per half
  constexpr int HSIZE  = (HA + 128) * 64;   // ushorts per slot
  constexpr int BOFF   = HA * 64;           // B region offset in slot
  constexpr int HLOADS = (BM == 256) ? 4 : 3;  // staging instrs/half/wave
  __shared__ unsigned short lds[5 * HSIZE]; // 160 KiB (BM=256) / 120 KiB

  const int tid  = threadIdx.x;
  const int wave = tid >> 6, lane = tid & 63;
  const int quad = lane >> 4, l16 = lane & 15;
  const int wm2 = (wave >> 2) * HA;         // wave's C-row base
  const int wn2 = (wave & 3) * 64;          // wave's C-col base
  const int ah  = wave >> 2;                // A-half parity for this wave
  const int bh  = (wave & 3) >> 1;          // B-half parity
  const int brow = (wave & 1) * 64;         // B row base within its half
  const int swz = l16 & 7;

  // bijective XCD-aware block swizzle (nwg % 8 == 0 for both modes)
  const int nwgx = gridDim.x;
  const int nwg  = nwgx * gridDim.y;
  const int orig = blockIdx.y * nwgx + blockIdx.x;
  const int bswz = (orig & 7) * (nwg >> 3) + (orig >> 3);
  const long mBase = (long)(bswz / nwgx) * BM;
  const long nBase = (long)(bswz % nwgx) * 256;

  // staging lane geometry: one instr = 8 rows x 64 cols, source col
  // pre-swizzled so linear LDS dest gets the chunk-XOR layout.
  const int lr  = lane >> 3;
  const int lks = ((lane & 7) ^ lr) * 8;
  const unsigned short* Abase = A + (mBase + lr) * (long)K + lks;
  const unsigned short* Bbase = B + (nBase + lr) * (long)K + lks;

  const int NT = K >> 6;   // 16 for both gemms

  // STAGE_PIECE(half, slot, piece): piece 0 = {A instr 0, B instr 0},
  // piece 1 = {A instr 1 (BM==256 only), B instr 1}.  Guard uniform.
#define STAGE_PIECE(HH, SL, P) do {                                                   \
    if ((HH) < 2 * NT) {                                                              \
      if (BM == 256 || (P) == 0) {                                                    \
        const int _ar = wave * (BM / 16) + (P) * 8;                                   \
        __builtin_amdgcn_global_load_lds(                                             \
            AS1(Abase + ((long)(((HH) & 1) * HA + _ar)) * K + (long)((HH) >> 1) * 64),\
            AS3(lds + (SL) * HSIZE + _ar * 64), 16, 0, 0);                            \
      }                                                                               \
      const int _br = wave * 16 + (P) * 8;                                            \
      __builtin_amdgcn_global_load_lds(                                               \
          AS1(Bbase + ((long)(((HH) & 1) * 128 + _br)) * K + (long)((HH) >> 1) * 64), \
          AS3(lds + (SL) * HSIZE + BOFF + _br * 64), 16, 0, 0);                       \
    }                                                                                 \
  } while (0)

  f32x4 acc[MR][4];
#pragma unroll
  for (int i = 0; i < MR; ++i)
#pragma unroll
    for (int j = 0; j < 4; ++j)
#pragma unroll
      for (int r = 0; r < 4; ++r) acc[i][j][r] = 0.f;

  // prologue: halves 0,1,2 into slots 0,1,2; drain 0,1 (half 2 in flight).
#pragma unroll
  for (int h = 0; h < 3; ++h) { STAGE_PIECE(h, h, 0); STAGE_PIECE(h, h, 1); }
  asm volatile("s_waitcnt vmcnt(%0)" :: "i"(HLOADS) : "memory");
  __builtin_amdgcn_s_barrier();

  int slA = ah, slB = bh;    // slots of this wave's A/B halves for tile T
  int s3 = 3, s4 = 4;        // slots of halves 2T+3, 2T+4
  for (int T = 0; T < NT; ++T) {
    const unsigned short* Ar = lds + slA * HSIZE;
    const unsigned short* Br = lds + slB * HSIZE + BOFF + brow * 64;
    bf16x8 bF[4];
#pragma unroll
    for (int q = 0; q < 4; ++q) {
      const int s = q >> 1, mh = q & 1;
      if (mh == 0) {
#pragma unroll
        for (int j = 0; j < 4; ++j)
          bF[j] = *(const bf16x8*)(Br + (j * 16 + l16) * 64 + (((s * 4 + quad) ^ swz) * 8));
      }
      bf16x8 aF[MR / 2];
#pragma unroll
      for (int t = 0; t < MR / 2; ++t)
        aF[t] = *(const bf16x8*)(Ar + ((mh * (MR / 2) + t) * 16 + l16) * 64 + (((s * 4 + quad) ^ swz) * 8));

      // stage one piece of half 2T+3 (q<2) or 2T+4 (q>=2)
      {
        const int hh = 2 * T + 3 + s;
        const int sl = s ? s4 : s3;
        STAGE_PIECE(hh, sl, mh);
      }
      if (q == 3) {
        if (T == NT - 2)     asm volatile("s_waitcnt vmcnt(0)" ::: "memory");
        else if (T < NT - 2) asm volatile("s_waitcnt vmcnt(%0)" :: "i"(HLOADS) : "memory");
      }
      __builtin_amdgcn_s_barrier();
      asm volatile("s_waitcnt lgkmcnt(0)" ::: "memory");
      __builtin_amdgcn_s_setprio(1);
#pragma unroll
      for (int t = 0; t < MR / 2; ++t)
#pragma unroll
        for (int j = 0; j < 4; ++j)
          acc[mh * (MR / 2) + t][j] =
              __builtin_amdgcn_mfma_f32_16x16x32_bf16(aF[t], bF[j], acc[mh * (MR / 2) + t][j], 0, 0, 0);
      __builtin_amdgcn_s_setprio(0);
      __builtin_amdgcn_s_barrier();
    }
    slA += 2; if (slA >= 5) slA -= 5;
    slB += 2; if (slB >= 5) slB -= 5;
    s3  += 2; if (s3  >= 5) s3  -= 5;
    s4  += 2; if (s4  >= 5) s4  -= 5;
  }
#undef STAGE_PIECE

  if (MODE == 1 && nBase >= 2048) {
    // V block: write transposed into vt[b][h][d][s]; r=0..3 -> s contiguous
#pragma unroll
    for (int j = 0; j < 4; ++j) {
      const int nG = (int)nBase + wn2 + j * 16 + l16;
      const float bv = bias[nG];
      const int hd = nG - 2048;
      const int hh = hd >> 6, dd = hd & 63;
#pragma unroll
      for (int i = 0; i < MR; ++i) {
        const int mG0 = (int)mBase + wm2 + i * 16 + quad * 4;
        const int bb = mG0 >> 11, ss = mG0 & 2047;
        ushort4 o;
        o.x = f2bf(acc[i][j][0] + bv);
        o.y = f2bf(acc[i][j][1] + bv);
        o.z = f2bf(acc[i][j][2] + bv);
        o.w = f2bf(acc[i][j][3] + bv);
        *(ushort4*)(vt + (((long)(bb * NHEAD + hh)) * HDIM + dd) * SLEN + ss) = o;
      }
    }
  } else {
#pragma unroll
    for (int j = 0; j < 4; ++j) {
      const long nG = nBase + wn2 + j * 16 + l16;
      const float bv = bias[nG];
#pragma unroll
      for (int i = 0; i < MR; ++i)
#pragma unroll
        for (int r = 0; r < 4; ++r) {
          const long mG = mBase + wm2 + i * 16 + quad * 4 + r;
          const float v = acc[i][j][r] + bv;
          if (MODE == 1) ((unsigned short*)Cout)[mG * ldc + nG] = f2bf(v);
          else           ((float*)Cout)[mG * ldc + nG] = v;
        }
    }
  }
}

// Banded-causal flash attention, S^T orientation, batched softmax.
// 128-query blocks (512 thr, 8 waves). qk: [B*S][2048] bf16 (Q|K),
// vT: [B*H][64][2048]. K and V staged in XOR-swizzled LDS (GEMM-proven
// conflict-free geometry: 128B-multiple row stride + 16B-chunk XOR).
__global__ __launch_bounds__(512, 4) void local_attn(
    const unsigned short* __restrict__ qk,
    const unsigned short* __restrict__ vT,
    unsigned short* __restrict__ outw)
{
  const int qb = blockIdx.x;   // 128-query tile
  const int h  = blockIdx.y;
  const int b  = blockIdx.z;
  const int tid = threadIdx.x;
  const int wave = tid >> 6, lane = tid & 63;
  const int quad = lane >> 4, l16 = lane & 15;

  __shared__ unsigned short Klds[256 * 64];   // [key][chunk ^ (key&7)]
  __shared__ unsigned short Vlds[64 * 256];   // [d][chunk ^ (d&7)] along key

  const int kwin0 = qb * 128 - WINSZ;         // global key of local key 0

  // --- K staging via global_load_lds (swizzled, clamped rows) ---
  {
    const int kr = lane >> 3, kc = lane & 7;
    const long colOff = 1024 + h * HDIM + ((kc ^ kr) * 8);
#pragma unroll
    for (int t = 0; t < 4; ++t) {
      const int u = wave * 4 + t;                 // unit of 8 keys (32 units)
      const int sk = max(kwin0 + u * 8 + kr, 0);  // clamp; junk masked later
      const unsigned short* g = qk + (long)(b * SLEN + sk) * 2048 + colOff;
      __builtin_amdgcn_global_load_lds(AS1(g), AS3(Klds + u * 512), 16, 0, 0);
    }
  }
  // --- V^T staging: coalesced reads from vT, XOR-swizzled LDS writes ---
  {
    const unsigned short* vbase = vT + ((long)(b * NHEAD + h)) * HDIM * SLEN;
#pragma unroll
    for (int t = 0; t < 4; ++t) {
      const int c = t * 512 + tid;          // [0, 2048): 64 d x 32 chunks
      const int d = c >> 5, k8 = c & 31;
      const int s0 = max(kwin0 + k8 * 8, 0);
      uint4 v = *(const uint4*)(vbase + (long)d * SLEN + s0);
      *(uint4*)(Vlds + d * 256 + ((k8 ^ (d & 7)) * 8)) = v;
    }
  }

  // Q fragments (B-operand): 16 queries per wave
  const int q0 = qb * 128 + wave * 16;
  const long qrow = (long)(b * SLEN + q0 + l16) * 2048 + h * HDIM;
  const bf16x8 qB0 = *(const bf16x8*)(qk + qrow + quad * 8);
  const bf16x8 qB1 = *(const bf16x8*)(qk + qrow + 32 + quad * 8);

  __syncthreads();

  // --- QK^T (S^T orientation): all 5 x 32 keys ---
  const int lbase = (wave * 16) & ~31;
  const int kx = l16 & 7;
  const int a0 = (quad ^ kx) * 8;
  const int a1 = ((4 + quad) ^ kx) * 8;
  f32x4 sc[5][2];
#pragma unroll
  for (int it = 0; it < 5; ++it) {
    const int l0 = lbase + it * 32;
#pragma unroll
    for (int half = 0; half < 2; ++half) {
      const unsigned short* kr_ = Klds + (l0 + half * 16 + l16) * 64;
      const bf16x8 kA0 = *(const bf16x8*)(kr_ + a0);
      const bf16x8 kA1 = *(const bf16x8*)(kr_ + a1);
      f32x4 s;
#pragma unroll
      for (int r = 0; r < 4; ++r) s[r] = 0.f;
      s = __builtin_amdgcn_mfma_f32_16x16x32_bf16(kA0, qB0, s, 0, 0, 0);
      s = __builtin_amdgcn_mfma_f32_16x16x32_bf16(kA1, qB1, s, 0, 0, 0);
      sc[it][half] = s;   // row = key_local = quad*4+r, col = query = l16
    }
  }

  // --- mask + scale; batched softmax (reduce over quads: 2 shfl steps) ---
  // Valid local keys for query: [qlocal - WINSZ, qlocal], clipped below
  // -kwin0 when staging clamped (qb==0 -> 128).
  const int qlocal = WINSZ + wave * 16 + l16;       // own query, local coords
  const int lo = max(wave * 16 + l16, kwin0 < 0 ? -kwin0 : 0);
  const int kb = lbase + quad * 4;
  float m = -3.0e38f;
#pragma unroll
  for (int it = 0; it < 5; ++it)
#pragma unroll
    for (int half = 0; half < 2; ++half)
#pragma unroll
      for (int r = 0; r < 4; ++r) {
        const int kl = kb + it * 32 + half * 16 + r;
        float v = sc[it][half][r] * 0.125f;
        v = (kl >= lo && kl <= qlocal) ? v : -3.0e38f;
        sc[it][half][r] = v;
        m = fmaxf(m, v);
      }
  m = fmaxf(m, __shfl_xor(m, 16, 64));
  m = fmaxf(m, __shfl_xor(m, 32, 64));

  float lsum = 0.f;
#pragma unroll
  for (int it = 0; it < 5; ++it)
#pragma unroll
    for (int half = 0; half < 2; ++half)
#pragma unroll
      for (int r = 0; r < 4; ++r) {
        const float e = __expf(sc[it][half][r] - m);
        sc[it][half][r] = e;
        lsum += e;
      }
  lsum += __shfl_xor(lsum, 16, 64);
  lsum += __shfl_xor(lsum, 32, 64);
  const float invl = 1.0f / lsum;

  // --- PV: O^T = V^T * P^T; P^T B-frag assembled via shuffles ---
  f32x4 Oacc[4];
#pragma unroll
  for (int dt = 0; dt < 4; ++dt)
#pragma unroll
    for (int r = 0; r < 4; ++r) Oacc[dt][r] = 0.f;

#pragma unroll
  for (int it = 0; it < 5; ++it) {
    const int l0 = lbase + it * 32;
    // pack this lane's 8 P values (4 per half) into bf16 pairs
    const unsigned int u0 = pack_bf(sc[it][0][0], sc[it][0][1]);
    const unsigned int u1 = pack_bf(sc[it][0][2], sc[it][0][3]);
    const unsigned int u2 = pack_bf(sc[it][1][0], sc[it][1][1]);
    const unsigned int u3 = pack_bf(sc[it][1][2], sc[it][1][3]);
    // gather B-frag: lane needs keys quad*8 + [0..7] of query l16
    unsigned int breg[4];
#pragma unroll
    for (int r = 0; r < 4; ++r) {
      const int srcl = ((quad & 1) * 2 + (r >> 1)) * 16 + l16;
      const unsigned int ga = __shfl((int)((r & 1) ? u1 : u0), srcl, 64);
      const unsigned int gb = __shfl((int)((r & 1) ? u3 : u2), srcl, 64);
      breg[r] = (quad >> 1) ? gb : ga;
    }
    union { unsigned int u[4]; bf16x8 v; } pB;
    pB.u[0] = breg[0]; pB.u[1] = breg[1]; pB.u[2] = breg[2]; pB.u[3] = breg[3];

    const int chBase = (l0 >> 3);                 // multiple of 4
#pragma unroll
    for (int dt = 0; dt < 4; ++dt) {
      const int ch = (chBase + quad) ^ kx;        // kx = l16&7 = d&7
      const bf16x8 vA = *(const bf16x8*)(Vlds + (dt * 16 + l16) * 256 + ch * 8);
      Oacc[dt] = __builtin_amdgcn_mfma_f32_16x16x32_bf16(vA, pB.v, Oacc[dt], 0, 0, 0);
    }
  }

  // --- epilogue: O^T C-layout; r=0..3 contiguous -> packed ushort4 stores ---
  const long obase = (long)(b * SLEN + q0 + l16) * EMB + h * HDIM;
#pragma unroll
  for (int dt = 0; dt < 4; ++dt) {
    ushort4 o;
    o.x = f2bf(Oacc[dt][0] * invl);
    o.y = f2bf(Oacc[dt][1] * invl);
    o.z = f2bf(Oacc[dt][2] * invl);
    o.w = f2bf(Oacc[dt][3] * invl);
    *(ushort4*)(outw + obase + dt * 16 + quad * 4) = o;
  }
}

extern "C" void kernel_launch(void* const* d_in, const int* in_sizes, int n_in,
                              void* d_out, int out_size, void* d_ws, size_t ws_size,
                              hipStream_t stream) {
  const float* x     = (const float*)d_in[0];
  const float* w_in  = (const float*)d_in[1];
  const float* b_in  = (const float*)d_in[2];
  const float* w_out = (const float*)d_in[3];
  const float* b_out = (const float*)d_in[4];
  float* out = (float*)d_out;

  char* ws = (char*)d_ws;
  unsigned short* xb    = (unsigned short*)(ws + 0);          // 16,777,216
  unsigned short* winb  = (unsigned short*)(ws + 16777216);   //  6,291,456
  unsigned short* woutb = (unsigned short*)(ws + 23068672);   //  2,097,152
  unsigned short* qkb   = (unsigned short*)(ws + 25165824);   // 8192x2048 bf16 = 33,554,432
  unsigned short* attn  = (unsigned short*)(ws + 58720256);   // 16,777,216
  unsigned short* vT    = (unsigned short*)(ws + 75497472);   // 16,777,216  (total 92,274,688)

  // fused converts: dst regions are contiguous (xb|winb|woutb)
  const long ncv = 8388608 + 3145728 + 1048576;               // 12,582,912
  cvt_all<<<(int)(ncv / 1024), 256, 0, stream>>>(x, w_in, w_out, xb);

  // qkv projection: Q,K -> qkb (stride 2048); V -> vT transposed
  gemm_nt<1, 256><<<dim3(3072 / 256, 8192 / 256), 512, 0, stream>>>(
      xb, winb, b_in, (void*)qkb, vT, 8192, 3072, 1024, 2048);

  local_attn<<<dim3(SLEN / 128, NHEAD, 4), 512, 0, stream>>>(qkb, vT, attn);

  // out-proj: BM=128 -> grid 4x64 = 256 blocks = exactly one full round
  gemm_nt<0, 128><<<dim3(1024 / 256, 8192 / 128), 512, 0, stream>>>(
      attn, woutb, b_out, (void*)out, nullptr, 8192, 1024, 1024, 1024);
}

// Round 7
// 201.528 us; speedup vs baseline: 1.1122x; 1.0559x over previous
//
#include <hip/hip_runtime.h>
#include <stdint.h>

#define SLEN 2048
#define EMB  1024
#define NHEAD 16
#define HDIM  64
#define WINSZ 128

typedef __attribute__((ext_vector_type(8))) __bf16 bf16x8;
typedef __attribute__((ext_vector_type(4))) float  f32x4;

__device__ __forceinline__ unsigned short f2bf(float f) {
  union { float f; unsigned int u; } v;
  v.f = f;
  unsigned int r = v.u + 0x7FFFu + ((v.u >> 16) & 1u);
  return (unsigned short)(r >> 16);
}

// pack two floats to bf16 pair (round-half-up; inputs finite, in [0,1] for P)
__device__ __forceinline__ unsigned int pack_bf(float a, float b) {
  union { float f; unsigned int u; } x, y;
  x.f = a; y.f = b;
  return ((y.u + 0x8000u) & 0xFFFF0000u) | ((x.u + 0x8000u) >> 16);
}

// One fused convert for x, w_in, w_out -> contiguous bf16 region at ws base.
// Grid-stride (2048 blocks) to trim launch/tail of the one-shot version.
__global__ void cvt_all(const float* __restrict__ x,
                        const float* __restrict__ wi,
                        const float* __restrict__ wo,
                        unsigned short* __restrict__ dst) {
  const long n0 = 8388608, n1 = n0 + 3145728, n2 = n1 + 1048576;
  const long stride = (long)gridDim.x * 256 * 4;
  for (long i = ((long)blockIdx.x * 256 + threadIdx.x) * 4; i < n2; i += stride) {
    const float* src; long off;
    if (i < n0)      { src = x;  off = i; }
    else if (i < n1) { src = wi; off = i - n0; }
    else             { src = wo; off = i - n1; }
    float4 f = *(const float4*)(src + off);
    ushort4 o;
    o.x = f2bf(f.x); o.y = f2bf(f.y); o.z = f2bf(f.z); o.w = f2bf(f.w);
    *(ushort4*)(dst + i) = o;
  }
}

#define AS1(p) (const __attribute__((address_space(1))) unsigned int*)((const void*)(p))
#define AS3(p) (__attribute__((address_space(3))) unsigned int*)((void*)(p))

// C = A[M,K] * B[N,K]^T + bias.  Tile 128(M) x 256(N), BK=64, 512 thr =
// 8 waves (2M x 4N), 64x64 per wave.  LDS: triple-buffered full K-tiles,
// A[128][64] + B[256][64] per buffer (row stride 128 B, chunk-XOR swizzle
// (chunk ^ (row&7)) -- measured ZERO bank conflicts; global_load_lds dest
// linear, source pre-swizzled).  Pipeline: tile T+2 staged during tile T,
// steady state s_waitcnt vmcnt(6), ONE barrier per K-tile.  This is the
// session-best measured GEMM structure (72.8 us QKV, reproduced twice);
// three deeper-pipeline rewrites (r1/r4/r6) were neutral-to-worse.
// MODE 0: fp32 out at ldc.  MODE 1 (qkv): cols <2048 -> bf16 at
// row-stride 2048; cols >=2048 (V) -> transposed into vt[b][h][d][s].
template <int MODE>
__global__ __launch_bounds__(512, 2) void gemm_nt(
    const unsigned short* __restrict__ A,
    const unsigned short* __restrict__ B,
    const float* __restrict__ bias,
    void* __restrict__ Cout,
    unsigned short* __restrict__ vt,
    int M, int N, int K, int ldc)
{
  // 3 buffers x (A 8192 + B 16384) ushorts = 144 KiB
  __shared__ unsigned short lds[73728];
  const int tid  = threadIdx.x;
  const int wave = tid >> 6, lane = tid & 63;
  const int quad = lane >> 4, l16 = lane & 15;
  const int wm = (wave >> 2) * 64, wn = (wave & 3) * 64;
  const int swz = l16 & 7;

  // bijective XCD-aware block swizzle (nwg % 8 == 0 for both modes)
  const int nwgx = gridDim.x;
  const int nwg  = nwgx * gridDim.y;
  const int orig = blockIdx.y * nwgx + blockIdx.x;
  const int bswz = (orig & 7) * (nwg >> 3) + (orig >> 3);
  const long mBase = (long)(bswz / nwgx) * 128;
  const long nBase = (long)(bswz % nwgx) * 256;

  // staging: each instr covers 8 rows x 64 cols; source col pre-swizzled
  const int lr  = lane >> 3;
  const int lks = ((lane & 7) ^ lr) * 8;
  const unsigned short* Abase = A + (mBase + lr) * (long)K + lks;
  const unsigned short* Bbase = B + (nBase + lr) * (long)K + lks;

  // H==0: A rows [w*16,w*16+8) + B rows [w*32,w*32+16)
  // H==1: A rows [w*16+8,..)   + B rows [w*32+16,w*32+32)
#define STAGE3(TT, dstOff, H) do {                                                     \
    const long _kc = (long)(TT) * 64;                                                  \
    const int _ar = wave * 16 + (H) * 8;                                               \
    const int _br = wave * 32 + (H) * 16;                                              \
    __builtin_amdgcn_global_load_lds(AS1(Abase + (long)_ar * K + _kc),                 \
                                     AS3(lds + (dstOff) + _ar * 64), 16, 0, 0);        \
    __builtin_amdgcn_global_load_lds(AS1(Bbase + (long)_br * K + _kc),                 \
                                     AS3(lds + (dstOff) + 8192 + _br * 64), 16, 0, 0); \
    __builtin_amdgcn_global_load_lds(AS1(Bbase + (long)(_br + 8) * K + _kc),           \
                                     AS3(lds + (dstOff) + 8192 + (_br + 8) * 64), 16, 0, 0); \
  } while (0)

  f32x4 acc[4][4];
#pragma unroll
  for (int i = 0; i < 4; ++i)
#pragma unroll
    for (int j = 0; j < 4; ++j)
#pragma unroll
      for (int r = 0; r < 4; ++r) acc[i][j][r] = 0.f;

  const int NT = K >> 6;   // >= 3

  // prologue: tiles 0 and 1 fully staged (12 loads/wave)
  STAGE3(0, 0, 0); STAGE3(0, 0, 1);
  STAGE3(1, 24576, 0); STAGE3(1, 24576, 1);

  int curOff = 0, stgOff = 49152;
  for (int T = 0; T < NT; ++T) {
    // tile-entry sync: own loads of tile T drained (allow T+1's 6 in
    // flight), then rendezvous -> all waves' tile-T loads resident.
    if (T + 1 < NT) asm volatile("s_waitcnt vmcnt(6)" ::: "memory");
    else            asm volatile("s_waitcnt vmcnt(0)" ::: "memory");
    __builtin_amdgcn_s_barrier();
    __builtin_amdgcn_sched_barrier(0);

    const unsigned short* Ar = lds + curOff;
    const unsigned short* Br = lds + curOff + 8192;
    const bool doStage = (T + 2 < NT);

#pragma unroll
    for (int s = 0; s < 2; ++s) {
      bf16x8 aF[4], bF[4];
#pragma unroll
      for (int i = 0; i < 4; ++i)
        aF[i] = *(const bf16x8*)(Ar + (wm + i * 16 + l16) * 64 + (((s * 4 + quad) ^ swz) * 8));
#pragma unroll
      for (int j = 0; j < 4; ++j)
        bF[j] = *(const bf16x8*)(Br + (wn + j * 16 + l16) * 64 + (((s * 4 + quad) ^ swz) * 8));
      if (doStage) STAGE3(T + 2, stgOff, s);   // dest buf holds dead tile T-1
      asm volatile("s_waitcnt lgkmcnt(0)" ::: "memory");
      __builtin_amdgcn_sched_barrier(0);
      __builtin_amdgcn_s_setprio(1);
#pragma unroll
      for (int i = 0; i < 4; ++i)
#pragma unroll
        for (int j = 0; j < 4; ++j)
          acc[i][j] = __builtin_amdgcn_mfma_f32_16x16x32_bf16(aF[i], bF[j], acc[i][j], 0, 0, 0);
      __builtin_amdgcn_s_setprio(0);
    }
    curOff = (curOff == 49152) ? 0 : curOff + 24576;
    stgOff = (stgOff == 49152) ? 0 : stgOff + 24576;
  }
#undef STAGE3

  if (MODE == 1 && nBase >= 2048) {
    // V block: write transposed into vt[b][h][d][s]; r=0..3 -> s contiguous
#pragma unroll
    for (int j = 0; j < 4; ++j) {
      const int nG = (int)nBase + wn + j * 16 + l16;
      const float bv = bias[nG];
      const int hd = nG - 2048;
      const int hh = hd >> 6, dd = hd & 63;
#pragma unroll
      for (int i = 0; i < 4; ++i) {
        const int mG0 = (int)mBase + wm + i * 16 + quad * 4;
        const int bb = mG0 >> 11, ss = mG0 & 2047;
        ushort4 o;
        o.x = f2bf(acc[i][j][0] + bv);
        o.y = f2bf(acc[i][j][1] + bv);
        o.z = f2bf(acc[i][j][2] + bv);
        o.w = f2bf(acc[i][j][3] + bv);
        *(ushort4*)(vt + (((long)(bb * NHEAD + hh)) * HDIM + dd) * SLEN + ss) = o;
      }
    }
  } else {
#pragma unroll
    for (int j = 0; j < 4; ++j) {
      const long nG = nBase + wn + j * 16 + l16;
      const float bv = bias[nG];
#pragma unroll
      for (int i = 0; i < 4; ++i)
#pragma unroll
        for (int r = 0; r < 4; ++r) {
          const long mG = mBase + wm + i * 16 + quad * 4 + r;
          const float v = acc[i][j][r] + bv;
          if (MODE == 1) ((unsigned short*)Cout)[mG * ldc + nG] = f2bf(v);
          else           ((float*)Cout)[mG * ldc + nG] = v;
        }
    }
  }
}

// Banded-causal flash attention, S^T orientation, batched softmax.
// 128-query blocks (512 thr, 8 waves). qk: [B*S][2048] bf16 (Q|K),
// vT: [B*H][64][2048]. K and V staged in XOR-swizzled LDS.
// r7: Q loads hoisted ahead of staging (latency overlap), setprio(1)
// around MFMA clusters (T5: measured +4-7% on attn, m191 — applicable
// here: 2 independent blocks/CU + post-sync wave divergence).
__global__ __launch_bounds__(512, 4) void local_attn(
    const unsigned short* __restrict__ qk,
    const unsigned short* __restrict__ vT,
    unsigned short* __restrict__ outw)
{
  const int qb = blockIdx.x;   // 128-query tile
  const int h  = blockIdx.y;
  const int b  = blockIdx.z;
  const int tid = threadIdx.x;
  const int wave = tid >> 6, lane = tid & 63;
  const int quad = lane >> 4, l16 = lane & 15;

  __shared__ unsigned short Klds[256 * 64];   // [key][chunk ^ (key&7)]
  __shared__ unsigned short Vlds[64 * 256];   // [d][chunk ^ (d&7)] along key

  const int kwin0 = qb * 128 - WINSZ;         // global key of local key 0

  // Q fragments first (B-operand, 16 queries/wave): issue these global
  // loads before the staging burst so their latency hides under it.
  const int q0 = qb * 128 + wave * 16;
  const long qrow = (long)(b * SLEN + q0 + l16) * 2048 + h * HDIM;
  const bf16x8 qB0 = *(const bf16x8*)(qk + qrow + quad * 8);
  const bf16x8 qB1 = *(const bf16x8*)(qk + qrow + 32 + quad * 8);

  // --- K staging via global_load_lds (swizzled, clamped rows) ---
  {
    const int kr = lane >> 3, kc = lane & 7;
    const long colOff = 1024 + h * HDIM + ((kc ^ kr) * 8);
#pragma unroll
    for (int t = 0; t < 4; ++t) {
      const int u = wave * 4 + t;                 // unit of 8 keys (32 units)
      const int sk = max(kwin0 + u * 8 + kr, 0);  // clamp; junk masked later
      const unsigned short* g = qk + (long)(b * SLEN + sk) * 2048 + colOff;
      __builtin_amdgcn_global_load_lds(AS1(g), AS3(Klds + u * 512), 16, 0, 0);
    }
  }
  // --- V^T staging: coalesced reads from vT, XOR-swizzled LDS writes ---
  {
    const unsigned short* vbase = vT + ((long)(b * NHEAD + h)) * HDIM * SLEN;
#pragma unroll
    for (int t = 0; t < 4; ++t) {
      const int c = t * 512 + tid;          // [0, 2048): 64 d x 32 chunks
      const int d = c >> 5, k8 = c & 31;
      const int s0 = max(kwin0 + k8 * 8, 0);
      uint4 v = *(const uint4*)(vbase + (long)d * SLEN + s0);
      *(uint4*)(Vlds + d * 256 + ((k8 ^ (d & 7)) * 8)) = v;
    }
  }

  __syncthreads();

  // --- QK^T (S^T orientation): all 5 x 32 keys ---
  const int lbase = (wave * 16) & ~31;
  const int kx = l16 & 7;
  const int a0 = (quad ^ kx) * 8;
  const int a1 = ((4 + quad) ^ kx) * 8;
  f32x4 sc[5][2];
#pragma unroll
  for (int it = 0; it < 5; ++it) {
    const int l0 = lbase + it * 32;
#pragma unroll
    for (int half = 0; half < 2; ++half) {
      const unsigned short* kr_ = Klds + (l0 + half * 16 + l16) * 64;
      const bf16x8 kA0 = *(const bf16x8*)(kr_ + a0);
      const bf16x8 kA1 = *(const bf16x8*)(kr_ + a1);
      f32x4 s;
#pragma unroll
      for (int r = 0; r < 4; ++r) s[r] = 0.f;
      __builtin_amdgcn_s_setprio(1);
      s = __builtin_amdgcn_mfma_f32_16x16x32_bf16(kA0, qB0, s, 0, 0, 0);
      s = __builtin_amdgcn_mfma_f32_16x16x32_bf16(kA1, qB1, s, 0, 0, 0);
      __builtin_amdgcn_s_setprio(0);
      sc[it][half] = s;   // row = key_local = quad*4+r, col = query = l16
    }
  }

  // --- mask + scale; batched softmax (reduce over quads: 2 shfl steps) ---
  // Valid local keys for query: [qlocal - WINSZ, qlocal], clipped below
  // -kwin0 when staging clamped (qb==0 -> 128).
  const int qlocal = WINSZ + wave * 16 + l16;       // own query, local coords
  const int lo = max(wave * 16 + l16, kwin0 < 0 ? -kwin0 : 0);
  const int kb = lbase + quad * 4;
  float m = -3.0e38f;
#pragma unroll
  for (int it = 0; it < 5; ++it)
#pragma unroll
    for (int half = 0; half < 2; ++half)
#pragma unroll
      for (int r = 0; r < 4; ++r) {
        const int kl = kb + it * 32 + half * 16 + r;
        float v = sc[it][half][r] * 0.125f;
        v = (kl >= lo && kl <= qlocal) ? v : -3.0e38f;
        sc[it][half][r] = v;
        m = fmaxf(m, v);
      }
  m = fmaxf(m, __shfl_xor(m, 16, 64));
  m = fmaxf(m, __shfl_xor(m, 32, 64));

  float lsum = 0.f;
#pragma unroll
  for (int it = 0; it < 5; ++it)
#pragma unroll
    for (int half = 0; half < 2; ++half)
#pragma unroll
      for (int r = 0; r < 4; ++r) {
        const float e = __expf(sc[it][half][r] - m);
        sc[it][half][r] = e;
        lsum += e;
      }
  lsum += __shfl_xor(lsum, 16, 64);
  lsum += __shfl_xor(lsum, 32, 64);
  const float invl = 1.0f / lsum;

  // --- PV: O^T = V^T * P^T; P^T B-frag assembled via shuffles ---
  f32x4 Oacc[4];
#pragma unroll
  for (int dt = 0; dt < 4; ++dt)
#pragma unroll
    for (int r = 0; r < 4; ++r) Oacc[dt][r] = 0.f;

#pragma unroll
  for (int it = 0; it < 5; ++it) {
    const int l0 = lbase + it * 32;
    // pack this lane's 8 P values (4 per half) into bf16 pairs
    const unsigned int u0 = pack_bf(sc[it][0][0], sc[it][0][1]);
    const unsigned int u1 = pack_bf(sc[it][0][2], sc[it][0][3]);
    const unsigned int u2 = pack_bf(sc[it][1][0], sc[it][1][1]);
    const unsigned int u3 = pack_bf(sc[it][1][2], sc[it][1][3]);
    // gather B-frag: lane needs keys quad*8 + [0..7] of query l16
    unsigned int breg[4];
#pragma unroll
    for (int r = 0; r < 4; ++r) {
      const int srcl = ((quad & 1) * 2 + (r >> 1)) * 16 + l16;
      const unsigned int ga = __shfl((int)((r & 1) ? u1 : u0), srcl, 64);
      const unsigned int gb = __shfl((int)((r & 1) ? u3 : u2), srcl, 64);
      breg[r] = (quad >> 1) ? gb : ga;
    }
    union { unsigned int u[4]; bf16x8 v; } pB;
    pB.u[0] = breg[0]; pB.u[1] = breg[1]; pB.u[2] = breg[2]; pB.u[3] = breg[3];

    const int chBase = (l0 >> 3);                 // multiple of 4
#pragma unroll
    for (int dt = 0; dt < 4; ++dt) {
      const int ch = (chBase + quad) ^ kx;        // kx = l16&7 = d&7
      const bf16x8 vA = *(const bf16x8*)(Vlds + (dt * 16 + l16) * 256 + ch * 8);
      __builtin_amdgcn_s_setprio(1);
      Oacc[dt] = __builtin_amdgcn_mfma_f32_16x16x32_bf16(vA, pB.v, Oacc[dt], 0, 0, 0);
      __builtin_amdgcn_s_setprio(0);
    }
  }

  // --- epilogue: O^T C-layout; r=0..3 contiguous -> packed ushort4 stores ---
  const long obase = (long)(b * SLEN + q0 + l16) * EMB + h * HDIM;
#pragma unroll
  for (int dt = 0; dt < 4; ++dt) {
    ushort4 o;
    o.x = f2bf(Oacc[dt][0] * invl);
    o.y = f2bf(Oacc[dt][1] * invl);
    o.z = f2bf(Oacc[dt][2] * invl);
    o.w = f2bf(Oacc[dt][3] * invl);
    *(ushort4*)(outw + obase + dt * 16 + quad * 4) = o;
  }
}

extern "C" void kernel_launch(void* const* d_in, const int* in_sizes, int n_in,
                              void* d_out, int out_size, void* d_ws, size_t ws_size,
                              hipStream_t stream) {
  const float* x     = (const float*)d_in[0];
  const float* w_in  = (const float*)d_in[1];
  const float* b_in  = (const float*)d_in[2];
  const float* w_out = (const float*)d_in[3];
  const float* b_out = (const float*)d_in[4];
  float* out = (float*)d_out;

  char* ws = (char*)d_ws;
  unsigned short* xb    = (unsigned short*)(ws + 0);          // 16,777,216
  unsigned short* winb  = (unsigned short*)(ws + 16777216);   //  6,291,456
  unsigned short* woutb = (unsigned short*)(ws + 23068672);   //  2,097,152
  unsigned short* qkb   = (unsigned short*)(ws + 25165824);   // 8192x2048 bf16 = 33,554,432
  unsigned short* attn  = (unsigned short*)(ws + 58720256);   // 16,777,216
  unsigned short* vT    = (unsigned short*)(ws + 75497472);   // 16,777,216  (total 92,274,688)

  // fused converts: dst regions are contiguous (xb|winb|woutb)
  cvt_all<<<2048, 256, 0, stream>>>(x, w_in, w_out, xb);

  // qkv projection: Q,K -> qkb (stride 2048); V -> vT transposed
  gemm_nt<1><<<dim3(3072 / 256, 8192 / 128), 512, 0, stream>>>(
      xb, winb, b_in, (void*)qkb, vT, 8192, 3072, 1024, 2048);

  local_attn<<<dim3(SLEN / 128, NHEAD, 4), 512, 0, stream>>>(qkb, vT, attn);

  gemm_nt<0><<<dim3(1024 / 256, 8192 / 128), 512, 0, stream>>>(
      attn, woutb, b_out, (void*)out, nullptr, 8192, 1024, 1024, 1024);
}